// Round 14
// baseline (440.194 us; speedup 1.0000x reference)
//
#include <hip/hip_runtime.h>
#include <cstddef>

// Problem constants
#define B_   4
#define NS_  96
#define T_   8
#define H_   256
#define N_   97      // NS + 1
#define NL_  6       // NUM_LAYERS
#define R_   388     // B_ * N_

// fast gates: v_exp_f32 (2^x) + v_rcp_f32
__device__ __forceinline__ float sigm(float x) {
    return __builtin_amdgcn_rcpf(1.0f + __builtin_amdgcn_exp2f(-1.44269504f * x));
}
__device__ __forceinline__ float tanh_f(float x) {
    return 1.0f - 2.0f * __builtin_amdgcn_rcpf(1.0f + __builtin_amdgcn_exp2f(2.88539008f * x));
}

// ============ prologue: 512-thr blocks ============
// bid<384: xz 64x128 tiles; 384-385: cz; 386-387: hw; 388: ck; 389..437: init (8 rows each).
__global__ __launch_bounds__(512) void prologue(
        const int* __restrict__ ids, const float* __restrict__ embed,
        const float* __restrict__ Wx_s, const float* __restrict__ b_s,
        const float* __restrict__ b_se, const float* __restrict__ Wx_e,
        const float* __restrict__ b_e, const float* __restrict__ W_sd,
        const float* __restrict__ b_sd, const float* __restrict__ Wh_e,
        const float* __restrict__ init_a, const float* __restrict__ init_b,
        float* __restrict__ xz, float* __restrict__ cz, float* __restrict__ ck,
        float* __restrict__ hw, float* __restrict__ c0, float* __restrict__ h0,
        float* __restrict__ p0) {
    int bid = blockIdx.x, t = threadIdx.x;
    if (bid < 384) {                      // xz = embed[ids] @ Wx_s + b_s, 64x128 tile
        __shared__ float As[64][260];
        __shared__ int ridx[64];
        int r0 = (bid >> 3) * 64, n0 = (bid & 7) * 128;
        if (t < 64) ridx[t] = ids[r0 + t];
        __syncthreads();
#pragma unroll
        for (int m = 0; m < 8; m++) {     // stage 64x256 (8 float4/thread)
            int L = m * 512 + t;
            int r = L >> 6, c4 = (L & 63) * 4;
            *(float4*)&As[r][c4] = *(const float4*)(embed + (size_t)ridx[r] * 256 + c4);
        }
        __syncthreads();
        int rg = t >> 5, cg = t & 31;     // 16 row-groups x 32 col-quads
        float acc[4][4] = {};
        const float* wp = Wx_s + n0 + 4 * cg;
#pragma unroll 2
        for (int kb = 0; kb < 64; kb++) {
            float4 w0 = *(const float4*)(wp + (size_t)(4 * kb + 0) * 1024);
            float4 w1 = *(const float4*)(wp + (size_t)(4 * kb + 1) * 1024);
            float4 w2 = *(const float4*)(wp + (size_t)(4 * kb + 2) * 1024);
            float4 w3 = *(const float4*)(wp + (size_t)(4 * kb + 3) * 1024);
#pragma unroll
            for (int i = 0; i < 4; i++) {
                float4 a = *(const float4*)&As[rg * 4 + i][4 * kb];
                acc[i][0] = fmaf(a.x, w0.x, acc[i][0]);
                acc[i][1] = fmaf(a.x, w0.y, acc[i][1]);
                acc[i][2] = fmaf(a.x, w0.z, acc[i][2]);
                acc[i][3] = fmaf(a.x, w0.w, acc[i][3]);
                acc[i][0] = fmaf(a.y, w1.x, acc[i][0]);
                acc[i][1] = fmaf(a.y, w1.y, acc[i][1]);
                acc[i][2] = fmaf(a.y, w1.z, acc[i][2]);
                acc[i][3] = fmaf(a.y, w1.w, acc[i][3]);
                acc[i][0] = fmaf(a.z, w2.x, acc[i][0]);
                acc[i][1] = fmaf(a.z, w2.y, acc[i][1]);
                acc[i][2] = fmaf(a.z, w2.z, acc[i][2]);
                acc[i][3] = fmaf(a.z, w2.w, acc[i][3]);
                acc[i][0] = fmaf(a.w, w3.x, acc[i][0]);
                acc[i][1] = fmaf(a.w, w3.y, acc[i][1]);
                acc[i][2] = fmaf(a.w, w3.z, acc[i][2]);
                acc[i][3] = fmaf(a.w, w3.w, acc[i][3]);
            }
        }
        int col = n0 + 4 * cg;
        float4 bv = *(const float4*)&b_s[col];
#pragma unroll
        for (int i = 0; i < 4; i++) {
            int r = r0 + rg * 4 + i;
            float4 o = make_float4(acc[i][0] + bv.x, acc[i][1] + bv.y,
                                   acc[i][2] + bv.z, acc[i][3] + bv.w);
            *(float4*)&xz[(size_t)r * 1024 + col] = o;
        }
    } else if (bid < 386) {               // cz[n] = b_e + b_se@Wx_e
        int n = (bid - 384) * 512 + t;
        float acc = b_e[n];
        for (int k = 0; k < 256; k++) acc = fmaf(b_se[k], Wx_e[(size_t)k * 1024 + n], acc);
        cz[n] = acc;
    } else if (bid < 388) {               // hw[n] = cz[n] + init_b@Wh_e
        int n = (bid - 386) * 512 + t;
        float acc = b_e[n];
        for (int k = 0; k < 256; k++) {
            acc = fmaf(b_se[k], Wx_e[(size_t)k * 1024 + n], acc);
            acc = fmaf(init_b[k], Wh_e[(size_t)k * 1024 + n], acc);
        }
        hw[n] = acc;
    } else if (bid == 388) {              // ck
        if (t < 256) {
            float acc = b_sd[t];
            for (int k = 0; k < 256; k++) acc = fmaf(b_se[k], W_sd[(size_t)k * 256 + t], acc);
            ck[t] = acc;
        }
    } else {                              // init c0/h0/p0: 8 rows per block
        int r0 = (bid - 389) * 8 + (t >> 8) * 4;
        int col = t & 255;
        float ia = init_a[col], ib = init_b[col];
#pragma unroll
        for (int rr = 0; rr < 4; rr++) {
            int row = r0 + rr;
            if (row < R_) {
                c0[(size_t)row * 256 + col] = ia;
                h0[(size_t)row * 256 + col] = ib;
                if (col == 0) p0[row] = ((row % N_) == 0) ? 1.0f : 0.0f;
            }
        }
    }
}

// ============ templated GEMM: C = A@W (+bias)(-subQ), p-gated rows, MT x 128 tile ============
template<int MT>
__global__ __launch_bounds__(256) void gemm_t(const float* __restrict__ A,
        const float* __restrict__ W, const float* __restrict__ bias,
        const float* __restrict__ subQ, const float* __restrict__ pgate,
        float* __restrict__ C, int R, int NC) {
    __shared__ float As[MT][260];
    __shared__ int anyflag;
    int t = threadIdx.x;
    int n0 = blockIdx.x * 128;
    int r0 = blockIdx.y * MT;
    if (pgate) {                          // skip blocks whose rows all have p == 0
        if (t == 0) anyflag = 0;
        __syncthreads();
        if (t < MT && r0 + t < R && pgate[r0 + t] != 0.0f) anyflag = 1;
        __syncthreads();
        if (!anyflag) return;
    }
#pragma unroll
    for (int m = 0; m < MT / 4; m++) {
        int L = m * 256 + t;
        int r = L >> 6, c4 = (L & 63) * 4;
        int rr = r0 + r;
        float4 v = make_float4(0.f, 0.f, 0.f, 0.f);
        if (rr < R) v = *(const float4*)(A + (size_t)rr * 256 + c4);
        *(float4*)&As[r][c4] = v;
    }
    __syncthreads();
    constexpr int RT = MT / 8;
    int rg = t >> 5, cg = t & 31;
    float acc[RT][4] = {};
    const float* wp = W + n0 + 4 * cg;
#pragma unroll 4
    for (int kb = 0; kb < 64; kb++) {
        float4 w0 = *(const float4*)(wp + (size_t)(4 * kb + 0) * NC);
        float4 w1 = *(const float4*)(wp + (size_t)(4 * kb + 1) * NC);
        float4 w2 = *(const float4*)(wp + (size_t)(4 * kb + 2) * NC);
        float4 w3 = *(const float4*)(wp + (size_t)(4 * kb + 3) * NC);
#pragma unroll
        for (int i = 0; i < RT; i++) {
            float4 a = *(const float4*)&As[rg * RT + i][4 * kb];
            acc[i][0] = fmaf(a.x, w0.x, acc[i][0]);
            acc[i][1] = fmaf(a.x, w0.y, acc[i][1]);
            acc[i][2] = fmaf(a.x, w0.z, acc[i][2]);
            acc[i][3] = fmaf(a.x, w0.w, acc[i][3]);
            acc[i][0] = fmaf(a.y, w1.x, acc[i][0]);
            acc[i][1] = fmaf(a.y, w1.y, acc[i][1]);
            acc[i][2] = fmaf(a.y, w1.z, acc[i][2]);
            acc[i][3] = fmaf(a.y, w1.w, acc[i][3]);
            acc[i][0] = fmaf(a.z, w2.x, acc[i][0]);
            acc[i][1] = fmaf(a.z, w2.y, acc[i][1]);
            acc[i][2] = fmaf(a.z, w2.z, acc[i][2]);
            acc[i][3] = fmaf(a.z, w2.w, acc[i][3]);
            acc[i][0] = fmaf(a.w, w3.x, acc[i][0]);
            acc[i][1] = fmaf(a.w, w3.y, acc[i][1]);
            acc[i][2] = fmaf(a.w, w3.z, acc[i][2]);
            acc[i][3] = fmaf(a.w, w3.w, acc[i][3]);
        }
    }
    int col = n0 + 4 * cg;
    float4 bv = make_float4(0.f, 0.f, 0.f, 0.f);
    if (bias) bv = *(const float4*)&bias[col];
#pragma unroll
    for (int i = 0; i < RT; i++) {
        int r = r0 + rg * RT + i;
        if (r < R) {
            float4 o = make_float4(acc[i][0] + bv.x, acc[i][1] + bv.y,
                                   acc[i][2] + bv.z, acc[i][3] + bv.w);
            if (subQ) {
                float4 s4 = *(const float4*)(subQ + (size_t)r * NC + col);
                o.x -= s4.x; o.y -= s4.y; o.z -= s4.z; o.w -= s4.w;
            }
            *(float4*)&C[(size_t)r * NC + col] = o;
        }
    }
}

// ============ merged q/r GEMM: bx<8 -> q (and ve0 = hw - q); else r (+rT) ============
__global__ __launch_bounds__(256) void qr_kernel(const float* __restrict__ S,
        const float* __restrict__ Wx_e, const float* __restrict__ W_sd,
        const float* __restrict__ hw, float* __restrict__ q, float* __restrict__ ve0,
        float* __restrict__ r_, float* __restrict__ rT) {
    __shared__ float As[16][260];
    int t = threadIdx.x;
    int bx = blockIdx.x;
    int r0 = blockIdx.y * 16;
#pragma unroll
    for (int m = 0; m < 4; m++) {
        int L = m * 256 + t;
        int r = L >> 6, c4 = (L & 63) * 4;
        int rr = r0 + r;
        float4 v = make_float4(0.f, 0.f, 0.f, 0.f);
        if (rr < R_) v = *(const float4*)(S + (size_t)rr * 256 + c4);
        *(float4*)&As[r][c4] = v;
    }
    __syncthreads();
    bool isq = bx < 8;
    const float* W = isq ? Wx_e : W_sd;
    int NC = isq ? 1024 : 256;
    int n0 = (isq ? bx : bx - 8) * 128;
    int rg = t >> 5, cg = t & 31;
    float acc[2][4] = {};
    const float* wp = W + n0 + 4 * cg;
#pragma unroll 4
    for (int kb = 0; kb < 64; kb++) {
        float4 w0 = *(const float4*)(wp + (size_t)(4 * kb + 0) * NC);
        float4 w1 = *(const float4*)(wp + (size_t)(4 * kb + 1) * NC);
        float4 w2 = *(const float4*)(wp + (size_t)(4 * kb + 2) * NC);
        float4 w3 = *(const float4*)(wp + (size_t)(4 * kb + 3) * NC);
#pragma unroll
        for (int i = 0; i < 2; i++) {
            float4 a = *(const float4*)&As[rg * 2 + i][4 * kb];
            acc[i][0] = fmaf(a.x, w0.x, acc[i][0]);
            acc[i][1] = fmaf(a.x, w0.y, acc[i][1]);
            acc[i][2] = fmaf(a.x, w0.z, acc[i][2]);
            acc[i][3] = fmaf(a.x, w0.w, acc[i][3]);
            acc[i][0] = fmaf(a.y, w1.x, acc[i][0]);
            acc[i][1] = fmaf(a.y, w1.y, acc[i][1]);
            acc[i][2] = fmaf(a.y, w1.z, acc[i][2]);
            acc[i][3] = fmaf(a.y, w1.w, acc[i][3]);
            acc[i][0] = fmaf(a.z, w2.x, acc[i][0]);
            acc[i][1] = fmaf(a.z, w2.y, acc[i][1]);
            acc[i][2] = fmaf(a.z, w2.z, acc[i][2]);
            acc[i][3] = fmaf(a.z, w2.w, acc[i][3]);
            acc[i][0] = fmaf(a.w, w3.x, acc[i][0]);
            acc[i][1] = fmaf(a.w, w3.y, acc[i][1]);
            acc[i][2] = fmaf(a.w, w3.z, acc[i][2]);
            acc[i][3] = fmaf(a.w, w3.w, acc[i][3]);
        }
    }
    int col = n0 + 4 * cg;
#pragma unroll
    for (int i = 0; i < 2; i++) {
        int r = r0 + rg * 2 + i;
        if (r < R_) {
            float4 o = make_float4(acc[i][0], acc[i][1], acc[i][2], acc[i][3]);
            if (isq) {
                *(float4*)&q[(size_t)r * 1024 + col] = o;
                float4 hwv = *(const float4*)&hw[col];   // ve0 = hw - q (h0 rows identical)
                float4 v0 = make_float4(hwv.x - o.x, hwv.y - o.y, hwv.z - o.z, hwv.w - o.w);
                *(float4*)&ve0[(size_t)r * 1024 + col] = v0;
            } else {
                *(float4*)&r_[(size_t)r * 256 + col] = o;
                int b = r / N_, n = r - b * N_;
                rT[((size_t)b * 256 + col + 0) * 128 + n] = o.x;
                rT[((size_t)b * 256 + col + 1) * 128 + n] = o.y;
                rT[((size_t)b * 256 + col + 2) * 128 + n] = o.z;
                rT[((size_t)b * 256 + col + 3) * 128 + n] = o.w;
            }
        }
    }
}

// ============ LSTM steps 0+1 fused: Wh streamed from global (L2-hot), h in LDS ============
__global__ __launch_bounds__(256) void lstm_first(const float* __restrict__ xz,
        const float* __restrict__ Wh, float* __restrict__ hbuf, float* __restrict__ cbuf) {
    __shared__ float h_s[32][260];
    __shared__ float zs[32][68];
    int t = threadIdx.x;
    int ct = blockIdx.x, st = blockIdx.y;
    int et0 = ct * 16, s0 = st * 32;
    int sp = t >> 4, cq = t & 15;
    int g = cq >> 2, q4 = cq & 3;
    int gcol = g * 256 + et0 + q4 * 4;
    // step 0 (h=c=0): h0 for all 32 seqs, each thread owns col t
    for (int seq = 0; seq < 32; seq++) {
        const float* z0 = xz + ((size_t)(s0 + seq) * T_) * 1024;
        float gi = z0[t], gg = z0[512 + t], go = z0[768 + t];
        float c0v = sigm(gi) * tanh_f(gg);
        h_s[seq][t] = sigm(go) * tanh_f(c0v);
    }
    float creg[2];
    {
        int e = et0 + (t & 15);
#pragma unroll
        for (int u = 0; u < 2; u++) {
            const float* z0 = xz + ((size_t)(s0 + sp + u * 16) * T_) * 1024;
            creg[u] = sigm(z0[e]) * tanh_f(z0[512 + e]);
        }
    }
    __syncthreads();
    // step-1 GEMM: W streamed from global (L2-resident), h from LDS as float2 pairs
    float4 a0 = *(const float4*)(xz + ((size_t)(s0 + sp) * T_ + 1) * 1024 + gcol);
    float4 a1 = *(const float4*)(xz + ((size_t)(s0 + sp + 16) * T_ + 1) * 1024 + gcol);
    const float* wg = Wh + gcol;
#pragma unroll 4
    for (int k2 = 0; k2 < 128; k2++) {
        float4 w0 = *(const float4*)(wg + (size_t)(2 * k2) * 1024);
        float4 w1 = *(const float4*)(wg + (size_t)(2 * k2 + 1) * 1024);
        float2 hA = *(const float2*)&h_s[sp][2 * k2];
        float2 hB = *(const float2*)&h_s[sp + 16][2 * k2];
        a0.x = fmaf(hA.x, w0.x, a0.x); a0.y = fmaf(hA.x, w0.y, a0.y);
        a0.z = fmaf(hA.x, w0.z, a0.z); a0.w = fmaf(hA.x, w0.w, a0.w);
        a0.x = fmaf(hA.y, w1.x, a0.x); a0.y = fmaf(hA.y, w1.y, a0.y);
        a0.z = fmaf(hA.y, w1.z, a0.z); a0.w = fmaf(hA.y, w1.w, a0.w);
        a1.x = fmaf(hB.x, w0.x, a1.x); a1.y = fmaf(hB.x, w0.y, a1.y);
        a1.z = fmaf(hB.x, w0.z, a1.z); a1.w = fmaf(hB.x, w0.w, a1.w);
        a1.x = fmaf(hB.y, w1.x, a1.x); a1.y = fmaf(hB.y, w1.y, a1.y);
        a1.z = fmaf(hB.y, w1.z, a1.z); a1.w = fmaf(hB.y, w1.w, a1.w);
    }
    *(float4*)&zs[sp][cq * 4] = a0;
    *(float4*)&zs[sp + 16][cq * 4] = a1;
    __syncthreads();
    {
        int e = t & 15;
#pragma unroll
        for (int u = 0; u < 2; u++) {
            int seq = sp + u * 16;
            float gi = zs[seq][e], gf = zs[seq][16 + e], gg = zs[seq][32 + e], go = zs[seq][48 + e];
            float cn = sigm(gf) * creg[u] + sigm(gi) * tanh_f(gg);
            size_t gidx = (size_t)(s0 + seq) * H_ + et0 + e;
            cbuf[gidx] = cn;
            hbuf[gidx] = sigm(go) * tanh_f(cn);
        }
    }
}

// ============ LSTM one step (2..7): Wh streamed from global, h staged in LDS ============
__global__ __launch_bounds__(256) void lstm_step(int step, const float* __restrict__ xz,
        const float* __restrict__ Wh, float* __restrict__ hbuf, float* __restrict__ cbuf) {
    __shared__ float h_s[32][260];
    __shared__ float zs[32][68];
    int t = threadIdx.x;
    int ct = blockIdx.x, st = blockIdx.y;
    int et0 = ct * 16, s0 = st * 32;
    int sp = t >> 4, cq = t & 15;
    int g = cq >> 2, q4 = cq & 3;
    int gcol = g * 256 + et0 + q4 * 4;
    float4 a0 = *(const float4*)(xz + ((size_t)(s0 + sp) * T_ + step) * 1024 + gcol);
    float4 a1 = *(const float4*)(xz + ((size_t)(s0 + sp + 16) * T_ + step) * 1024 + gcol);
#pragma unroll
    for (int m = 0; m < 8; m++) {        // stage h stripe (32x256)
        int L = m * 256 + t;
        int seq = L >> 6, c4 = (L & 63) * 4;
        *(float4*)&h_s[seq][c4] = *(const float4*)&hbuf[(size_t)(s0 + seq) * H_ + c4];
    }
    __syncthreads();
    const float* wg = Wh + gcol;
#pragma unroll 4
    for (int k2 = 0; k2 < 128; k2++) {
        float4 w0 = *(const float4*)(wg + (size_t)(2 * k2) * 1024);
        float4 w1 = *(const float4*)(wg + (size_t)(2 * k2 + 1) * 1024);
        float2 hA = *(const float2*)&h_s[sp][2 * k2];
        float2 hB = *(const float2*)&h_s[sp + 16][2 * k2];
        a0.x = fmaf(hA.x, w0.x, a0.x); a0.y = fmaf(hA.x, w0.y, a0.y);
        a0.z = fmaf(hA.x, w0.z, a0.z); a0.w = fmaf(hA.x, w0.w, a0.w);
        a0.x = fmaf(hA.y, w1.x, a0.x); a0.y = fmaf(hA.y, w1.y, a0.y);
        a0.z = fmaf(hA.y, w1.z, a0.z); a0.w = fmaf(hA.y, w1.w, a0.w);
        a1.x = fmaf(hB.x, w0.x, a1.x); a1.y = fmaf(hB.x, w0.y, a1.y);
        a1.z = fmaf(hB.x, w0.z, a1.z); a1.w = fmaf(hB.x, w0.w, a1.w);
        a1.x = fmaf(hB.y, w1.x, a1.x); a1.y = fmaf(hB.y, w1.y, a1.y);
        a1.z = fmaf(hB.y, w1.z, a1.z); a1.w = fmaf(hB.y, w1.w, a1.w);
    }
    *(float4*)&zs[sp][cq * 4] = a0;
    *(float4*)&zs[sp + 16][cq * 4] = a1;
    __syncthreads();
    {
        int e = t & 15;
#pragma unroll
        for (int u = 0; u < 2; u++) {
            int seq = sp + u * 16;
            float gi = zs[seq][e], gf = zs[seq][16 + e], gg = zs[seq][32 + e], go = zs[seq][48 + e];
            size_t gidx = (size_t)(s0 + seq) * H_ + et0 + e;
            float cnew = sigm(gf) * cbuf[gidx] + sigm(gi) * tanh_f(gg);
            cbuf[gidx] = cnew;
            hbuf[gidx] = sigm(go) * tanh_f(cnew);
        }
    }
}

// ============ cumsum: stage whole batch in LDS, scan in-LDS ============
__global__ __launch_bounds__(1024) void cumsum_k(const float* __restrict__ stmt,
                                                 float* __restrict__ pref) {
    __shared__ float buf[96][256];       // 98.3 KB
    int b = blockIdx.x, t = threadIdx.x;
#pragma unroll
    for (int m = 0; m < 6; m++) {        // 6144 float4, coalesced, independent
        int L = m * 1024 + t;
        int r = L >> 6, c4 = (L & 63) * 4;
        *(float4*)&buf[r][c4] = *(const float4*)(stmt + ((size_t)b * NS_ + r) * 256 + c4);
    }
    __syncthreads();
    if (t < 256) {
        float run = 0.0f;
        pref[((size_t)b * N_) * H_ + t] = 0.0f;
        for (int n = 1; n < N_; n++) {
            run += buf[n - 1][t];
            pref[((size_t)b * N_ + n) * H_ + t] = run;
        }
    }
}

// ============ ONCE: logits + masked softmax (layer-invariant) ============
__global__ void softmax_once(const float* __restrict__ r, const float* __restrict__ rT,
                             const float* __restrict__ ck, const float* __restrict__ Wd1,
                             const int* __restrict__ code_length,
                             float* __restrict__ spT_mid, float* __restrict__ spT0,
                             float* __restrict__ spT5) {
    __shared__ float ri[H_], ckl[H_], wd[H_];
    __shared__ float part[8][128];
    __shared__ float red[128];
    int t = threadIdx.x;             // 0..1023
    int j = t & 127, half = t >> 7;
    int bi = blockIdx.x;
    int b = bi / N_, i = bi % N_;
    if (t < H_) {
        ri[t] = r[(size_t)bi * H_ + t];
        ckl[t] = ck[t];
        wd[t] = Wd1[256 + t];
    }
    __syncthreads();
    int len = code_length[b] / T_;
    bool valid = (j < N_) && ((j > i && j <= len) || (j == len));
    float acc = 0.0f;
    if (valid) {
        const float* rTb = rT + (size_t)b * H_ * 128 + j;
        int h0 = half * 32;
#pragma unroll 4
        for (int hh = 0; hh < 32; hh++) {
            int h = h0 + hh;
            float v = rTb[(size_t)h * 128] - ri[h] + ckl[h];
            acc = fmaf(fmaxf(v, 0.0f), wd[h], acc);
        }
    }
    part[half][j] = acc;
    __syncthreads();
    float logit = -3.0e38f;
    if (t < 128) {
        if (valid)
            logit = part[0][j] + part[1][j] + part[2][j] + part[3][j]
                  + part[4][j] + part[5][j] + part[6][j] + part[7][j];
        red[j] = logit;
    }
    __syncthreads();
    for (int off = 64; off; off >>= 1) {
        if (t < off) red[t] = fmaxf(red[t], red[t + off]);
        __syncthreads();
    }
    float m = red[0];
    __syncthreads();
    float e = (t < 128 && valid) ? __builtin_amdgcn_exp2f(1.44269504f * (logit - m)) : 0.0f;
    if (t < 128) red[j] = e;
    __syncthreads();
    for (int off = 64; off; off >>= 1) {
        if (t < off) red[t] += red[t + off];
        __syncthreads();
    }
    float s = red[0];
    if (t < 128 && j < N_) {
        size_t o = ((size_t)b * N_ + j) * 128 + i;
        spT_mid[o] = e / s;
        spT0[o] = (j == 1) ? 1.0f : 0.0f;
        spT5[o] = (j == len) ? 1.0f : 0.0f;
    }
}

// ============ per-layer aggregate: gates = q[j] + ve[i]; 512 thr ============
__global__ __launch_bounds__(512) void aggregate(const float* __restrict__ q,
        const float* __restrict__ ve, const float* __restrict__ spT,
        const float* __restrict__ p, const float* __restrict__ cc,
        const float* __restrict__ hc, float* __restrict__ cn,
        float* __restrict__ hn, float* __restrict__ pn) {
    __shared__ float qj[1024];
    __shared__ float wcol[128];
    __shared__ float red[128];
    __shared__ int vlist[128];
    __shared__ int nv_s;
    __shared__ float parts[2][2][H_];
    int t = threadIdx.x;
    int bj = blockIdx.x;
    int b = bj / N_, j = bj - b * N_;
    if (t < 128) {
        float wv = (t < N_) ? spT[(size_t)bj * 128 + t] * p[b * N_ + t] : 0.f;
        wcol[t] = wv;
        red[t] = wv;
    }
    __syncthreads();
    if (t == 0) {
        int nv = 0;
        for (int i = 0; i < N_; i++)
            if (wcol[i] != 0.0f) vlist[nv++] = i;
        nv_s = nv;
    }
    __syncthreads();
    for (int off = 64; off; off >>= 1) {
        if (t < off) red[t] += red[t + off];
        __syncthreads();
    }
    float wsum = red[0];
    if (wsum == 0.0f) {
        if (t < 256) {
            cn[(size_t)bj * H_ + t] = 0.0f;
            hn[(size_t)bj * H_ + t] = 0.0f;
            if (t == 0) pn[bj] = 0.0f;
        }
        return;
    }
    qj[t] = q[(size_t)bj * 1024 + t];
    qj[512 + t] = q[(size_t)bj * 1024 + 512 + t];
    __syncthreads();
    int hh = t & 255, vs = t >> 8;
    int nv = nv_s;
    float ac = 0.f, ah = 0.f;
    for (int v = vs; v < nv; v += 2) {
        int i = vlist[v];
        float wv = wcol[i];
        size_t rowi = (size_t)b * N_ + i;
        if (j > i) {
            const float* vei = ve + rowi * 1024;
            float gi = qj[hh] + vei[hh];
            float gf = qj[256 + hh] + vei[256 + hh];
            float gg = qj[512 + hh] + vei[512 + hh];
            float go = qj[768 + hh] + vei[768 + hh];
            float c2 = cc[rowi * H_ + hh];
            float cp = sigm(gf) * c2 + sigm(gi) * tanh_f(gg);
            float hp = sigm(go) * tanh_f(cp);
            ac = fmaf(wv, cp, ac);
            ah = fmaf(wv, hp, ah);
        } else {
            ac = fmaf(wv, cc[rowi * H_ + hh], ac);
            ah = fmaf(wv, hc[rowi * H_ + hh], ah);
        }
    }
    parts[vs][0][hh] = ac;
    parts[vs][1][hh] = ah;
    __syncthreads();
    if (t < 256) {
        float inv = __builtin_amdgcn_rcpf(wsum + 1e-7f);
        cn[(size_t)bj * H_ + t] = (parts[0][0][t] + parts[1][0][t]) * inv;
        hn[(size_t)bj * H_ + t] = (parts[0][1][t] + parts[1][1][t]) * inv;
        if (t == 0) pn[bj] = wsum;
    }
}

// ---------------- host launcher ----------------

extern "C" void kernel_launch(void* const* d_in, const int* in_sizes, int n_in,
                              void* d_out, int out_size, void* d_ws, size_t ws_size,
                              hipStream_t stream) {
    const int*   code_statements = (const int*)d_in[0];
    const int*   code_length = (const int*)d_in[1];
    const float* embed = (const float*)d_in[2];
    const float* Wx_s = (const float*)d_in[3];
    const float* Wh_s = (const float*)d_in[4];
    const float* b_s  = (const float*)d_in[5];
    const float* W_se = (const float*)d_in[6];
    const float* b_se = (const float*)d_in[7];
    const float* Wx_e = (const float*)d_in[8];
    const float* Wh_e = (const float*)d_in[9];
    const float* b_e  = (const float*)d_in[10];
    const float* W_sd = (const float*)d_in[13];
    const float* b_sd = (const float*)d_in[14];
    const float* W_d1 = (const float*)d_in[15];
    // d_in[11] W_hk, d_in[12] b_hk, d_in[16] b_d1: softmax-invariant -> unused
    const float* init_a = (const float*)d_in[17];
    const float* init_b = (const float*)d_in[18];
    float* out = (float*)d_out;

    float* wsf = (float*)d_ws;
    size_t off = 0;
    auto alloc = [&](size_t n) { float* p = wsf + off; off += n; return p; };
    float* cz = alloc(1024);
    float* ck = alloc(256);
    float* hw = alloc(1024);             // init_b@Wh_e + cz
    float* xz = alloc((size_t)3072 * 1024);
    float* stmt = alloc(384 * 256);      // LSTM h buffer
    float* cls = alloc(384 * 256);       // LSTM cell state
    float* pref = alloc(R_ * 256);
    float* s_   = alloc(R_ * 256);       // pref @ W_se
    float* q  = alloc(R_ * 1024);
    float* r_ = alloc(R_ * 256);
    float* rT = alloc(4 * 256 * 128);
    float* ve = alloc(R_ * 1024);        // h@Wh_e + cz - q
    float* spT_mid = alloc(R_ * 128);
    float* spT0    = alloc(R_ * 128);
    float* spT5    = alloc(R_ * 128);
    float* p0 = alloc(R_);
    float* p1 = alloc(R_);
    float* c0 = alloc(R_ * 256);
    float* c1 = alloc(R_ * 256);
    float* h0 = alloc(R_ * 256);
    float* h1 = alloc(R_ * 256);

    // one prologue launch: xz (64x128 tiles) + cz/ck/hw + state init
    prologue<<<dim3(438), 512, 0, stream>>>(code_statements, embed, Wx_s, b_s,
                                            b_se, Wx_e, b_e, W_sd, b_sd, Wh_e,
                                            init_a, init_b, xz, cz, ck, hw, c0, h0, p0);
    // LSTM: steps 0+1 fused, then 2..7 (Wh streamed from global)
    lstm_first<<<dim3(16, 12), 256, 0, stream>>>(xz, Wh_s, stmt, cls);
    for (int step = 2; step < T_; step++)
        lstm_step<<<dim3(16, 12), 256, 0, stream>>>(step, xz, Wh_s, stmt, cls);
    cumsum_k<<<dim3(4), 1024, 0, stream>>>(stmt, pref);
    gemm_t<16><<<dim3(2, 25), 256, 0, stream>>>(pref, W_se, nullptr, nullptr, nullptr,
                                                s_, R_, 256);
    qr_kernel<<<dim3(10, 25), 256, 0, stream>>>(s_, Wx_e, W_sd, hw, q, ve, r_, rT);
    softmax_once<<<dim3(R_), 1024, 0, stream>>>(r_, rT, ck, W_d1, code_length,
                                                spT_mid, spT0, spT5);

    // execution layers (ve0 already produced by qr_kernel)
    for (int layer = 0; layer < NL_; layer++) {
        bool odd = (layer & 1);
        float* pc = odd ? p1 : p0;
        float* pn = odd ? p0 : p1;
        float* cc = odd ? c1 : c0;
        float* cn = odd ? c0 : c1;
        float* hc = odd ? h1 : h0;
        float* hn = odd ? h0 : h1;
        if (layer == NL_ - 1) hn = out;  // final h straight to d_out
        const float* spT = (layer == 0) ? spT0 : (layer == NL_ - 1) ? spT5 : spT_mid;
        aggregate<<<dim3(R_), 512, 0, stream>>>(q, ve, spT, pc, cc, hc, cn, hn, pn);
        if (layer < NL_ - 1)
            gemm_t<16><<<dim3(8, 25), 256, 0, stream>>>(hn, Wh_e, cz, q, pn,
                                                        ve, R_, 1024);
    }
}

// Round 15
// 414.049 us; speedup vs baseline: 1.0631x; 1.0631x over previous
//
#include <hip/hip_runtime.h>
#include <cstddef>

// Problem constants
#define B_   4
#define NS_  96
#define T_   8
#define H_   256
#define N_   97      // NS + 1
#define NL_  6       // NUM_LAYERS
#define R_   388     // B_ * N_

// fast gates: v_exp_f32 (2^x) + v_rcp_f32
__device__ __forceinline__ float sigm(float x) {
    return __builtin_amdgcn_rcpf(1.0f + __builtin_amdgcn_exp2f(-1.44269504f * x));
}
__device__ __forceinline__ float tanh_f(float x) {
    return 1.0f - 2.0f * __builtin_amdgcn_rcpf(1.0f + __builtin_amdgcn_exp2f(2.88539008f * x));
}

// ============ prologue v2: 512-thr blocks ============
// bid<384: xz 64x128 tiles; 384-385: cz; 386-387: hw; 388: ck; 389..437: init (8 rows each).
__global__ __launch_bounds__(512) void prologue(
        const int* __restrict__ ids, const float* __restrict__ embed,
        const float* __restrict__ Wx_s, const float* __restrict__ b_s,
        const float* __restrict__ b_se, const float* __restrict__ Wx_e,
        const float* __restrict__ b_e, const float* __restrict__ W_sd,
        const float* __restrict__ b_sd, const float* __restrict__ Wh_e,
        const float* __restrict__ init_a, const float* __restrict__ init_b,
        float* __restrict__ xz, float* __restrict__ cz, float* __restrict__ ck,
        float* __restrict__ hw, float* __restrict__ c0, float* __restrict__ h0,
        float* __restrict__ p0) {
    int bid = blockIdx.x, t = threadIdx.x;
    if (bid < 384) {                      // xz = embed[ids] @ Wx_s + b_s, 64x128 tile
        __shared__ float As[64][260];
        __shared__ int ridx[64];
        int r0 = (bid >> 3) * 64, n0 = (bid & 7) * 128;
        if (t < 64) ridx[t] = ids[r0 + t];
        __syncthreads();
#pragma unroll
        for (int m = 0; m < 8; m++) {     // stage 64x256 (8 float4/thread)
            int L = m * 512 + t;
            int r = L >> 6, c4 = (L & 63) * 4;
            *(float4*)&As[r][c4] = *(const float4*)(embed + (size_t)ridx[r] * 256 + c4);
        }
        __syncthreads();
        int rg = t >> 5, cg = t & 31;     // 16 row-groups x 32 col-quads
        float acc[4][4] = {};
        const float* wp = Wx_s + n0 + 4 * cg;
#pragma unroll 2
        for (int kb = 0; kb < 64; kb++) {
            float4 w0 = *(const float4*)(wp + (size_t)(4 * kb + 0) * 1024);
            float4 w1 = *(const float4*)(wp + (size_t)(4 * kb + 1) * 1024);
            float4 w2 = *(const float4*)(wp + (size_t)(4 * kb + 2) * 1024);
            float4 w3 = *(const float4*)(wp + (size_t)(4 * kb + 3) * 1024);
#pragma unroll
            for (int i = 0; i < 4; i++) {
                float4 a = *(const float4*)&As[rg * 4 + i][4 * kb];
                acc[i][0] = fmaf(a.x, w0.x, acc[i][0]);
                acc[i][1] = fmaf(a.x, w0.y, acc[i][1]);
                acc[i][2] = fmaf(a.x, w0.z, acc[i][2]);
                acc[i][3] = fmaf(a.x, w0.w, acc[i][3]);
                acc[i][0] = fmaf(a.y, w1.x, acc[i][0]);
                acc[i][1] = fmaf(a.y, w1.y, acc[i][1]);
                acc[i][2] = fmaf(a.y, w1.z, acc[i][2]);
                acc[i][3] = fmaf(a.y, w1.w, acc[i][3]);
                acc[i][0] = fmaf(a.z, w2.x, acc[i][0]);
                acc[i][1] = fmaf(a.z, w2.y, acc[i][1]);
                acc[i][2] = fmaf(a.z, w2.z, acc[i][2]);
                acc[i][3] = fmaf(a.z, w2.w, acc[i][3]);
                acc[i][0] = fmaf(a.w, w3.x, acc[i][0]);
                acc[i][1] = fmaf(a.w, w3.y, acc[i][1]);
                acc[i][2] = fmaf(a.w, w3.z, acc[i][2]);
                acc[i][3] = fmaf(a.w, w3.w, acc[i][3]);
            }
        }
        int col = n0 + 4 * cg;
        float4 bv = *(const float4*)&b_s[col];
#pragma unroll
        for (int i = 0; i < 4; i++) {
            int r = r0 + rg * 4 + i;
            float4 o = make_float4(acc[i][0] + bv.x, acc[i][1] + bv.y,
                                   acc[i][2] + bv.z, acc[i][3] + bv.w);
            *(float4*)&xz[(size_t)r * 1024 + col] = o;
        }
    } else if (bid < 386) {               // cz[n] = b_e + b_se@Wx_e
        int n = (bid - 384) * 512 + t;
        float acc = b_e[n];
        for (int k = 0; k < 256; k++) acc = fmaf(b_se[k], Wx_e[(size_t)k * 1024 + n], acc);
        cz[n] = acc;
    } else if (bid < 388) {               // hw[n] = cz[n] + init_b@Wh_e
        int n = (bid - 386) * 512 + t;
        float acc = b_e[n];
        for (int k = 0; k < 256; k++) {
            acc = fmaf(b_se[k], Wx_e[(size_t)k * 1024 + n], acc);
            acc = fmaf(init_b[k], Wh_e[(size_t)k * 1024 + n], acc);
        }
        hw[n] = acc;
    } else if (bid == 388) {              // ck
        if (t < 256) {
            float acc = b_sd[t];
            for (int k = 0; k < 256; k++) acc = fmaf(b_se[k], W_sd[(size_t)k * 256 + t], acc);
            ck[t] = acc;
        }
    } else {                              // init c0/h0/p0: 8 rows per block
        int r0 = (bid - 389) * 8 + (t >> 8) * 4;
        int col = t & 255;
        float ia = init_a[col], ib = init_b[col];
#pragma unroll
        for (int rr = 0; rr < 4; rr++) {
            int row = r0 + rr;
            if (row < R_) {
                c0[(size_t)row * 256 + col] = ia;
                h0[(size_t)row * 256 + col] = ib;
                if (col == 0) p0[row] = ((row % N_) == 0) ? 1.0f : 0.0f;
            }
        }
    }
}

// ============ templated GEMM: C = A@W (+bias)(-subQ), p-gated rows, MT x 128 tile ============
template<int MT>
__global__ __launch_bounds__(256) void gemm_t(const float* __restrict__ A,
        const float* __restrict__ W, const float* __restrict__ bias,
        const float* __restrict__ subQ, const float* __restrict__ pgate,
        float* __restrict__ C, int R, int NC) {
    __shared__ float As[MT][260];
    __shared__ int anyflag;
    int t = threadIdx.x;
    int n0 = blockIdx.x * 128;
    int r0 = blockIdx.y * MT;
    if (pgate) {                          // skip blocks whose rows all have p == 0
        if (t == 0) anyflag = 0;
        __syncthreads();
        if (t < MT && r0 + t < R && pgate[r0 + t] != 0.0f) anyflag = 1;
        __syncthreads();
        if (!anyflag) return;
    }
#pragma unroll
    for (int m = 0; m < MT / 4; m++) {
        int L = m * 256 + t;
        int r = L >> 6, c4 = (L & 63) * 4;
        int rr = r0 + r;
        float4 v = make_float4(0.f, 0.f, 0.f, 0.f);
        if (rr < R) v = *(const float4*)(A + (size_t)rr * 256 + c4);
        *(float4*)&As[r][c4] = v;
    }
    __syncthreads();
    constexpr int RT = MT / 8;
    int rg = t >> 5, cg = t & 31;
    float acc[RT][4] = {};
    const float* wp = W + n0 + 4 * cg;
#pragma unroll 2
    for (int kb = 0; kb < 64; kb++) {
        float4 w0 = *(const float4*)(wp + (size_t)(4 * kb + 0) * NC);
        float4 w1 = *(const float4*)(wp + (size_t)(4 * kb + 1) * NC);
        float4 w2 = *(const float4*)(wp + (size_t)(4 * kb + 2) * NC);
        float4 w3 = *(const float4*)(wp + (size_t)(4 * kb + 3) * NC);
#pragma unroll
        for (int i = 0; i < RT; i++) {
            float4 a = *(const float4*)&As[rg * RT + i][4 * kb];
            acc[i][0] = fmaf(a.x, w0.x, acc[i][0]);
            acc[i][1] = fmaf(a.x, w0.y, acc[i][1]);
            acc[i][2] = fmaf(a.x, w0.z, acc[i][2]);
            acc[i][3] = fmaf(a.x, w0.w, acc[i][3]);
            acc[i][0] = fmaf(a.y, w1.x, acc[i][0]);
            acc[i][1] = fmaf(a.y, w1.y, acc[i][1]);
            acc[i][2] = fmaf(a.y, w1.z, acc[i][2]);
            acc[i][3] = fmaf(a.y, w1.w, acc[i][3]);
            acc[i][0] = fmaf(a.z, w2.x, acc[i][0]);
            acc[i][1] = fmaf(a.z, w2.y, acc[i][1]);
            acc[i][2] = fmaf(a.z, w2.z, acc[i][2]);
            acc[i][3] = fmaf(a.z, w2.w, acc[i][3]);
            acc[i][0] = fmaf(a.w, w3.x, acc[i][0]);
            acc[i][1] = fmaf(a.w, w3.y, acc[i][1]);
            acc[i][2] = fmaf(a.w, w3.z, acc[i][2]);
            acc[i][3] = fmaf(a.w, w3.w, acc[i][3]);
        }
    }
    int col = n0 + 4 * cg;
    float4 bv = make_float4(0.f, 0.f, 0.f, 0.f);
    if (bias) bv = *(const float4*)&bias[col];
#pragma unroll
    for (int i = 0; i < RT; i++) {
        int r = r0 + rg * RT + i;
        if (r < R) {
            float4 o = make_float4(acc[i][0] + bv.x, acc[i][1] + bv.y,
                                   acc[i][2] + bv.z, acc[i][3] + bv.w);
            if (subQ) {
                float4 s4 = *(const float4*)(subQ + (size_t)r * NC + col);
                o.x -= s4.x; o.y -= s4.y; o.z -= s4.z; o.w -= s4.w;
            }
            *(float4*)&C[(size_t)r * NC + col] = o;
        }
    }
}

// ============ merged q/r GEMM: bx<8 -> q (and ve0 = hw - q); else r (+rT) ============
__global__ __launch_bounds__(256) void qr_kernel(const float* __restrict__ S,
        const float* __restrict__ Wx_e, const float* __restrict__ W_sd,
        const float* __restrict__ hw, float* __restrict__ q, float* __restrict__ ve0,
        float* __restrict__ r_, float* __restrict__ rT) {
    __shared__ float As[16][260];
    int t = threadIdx.x;
    int bx = blockIdx.x;
    int r0 = blockIdx.y * 16;
#pragma unroll
    for (int m = 0; m < 4; m++) {
        int L = m * 256 + t;
        int r = L >> 6, c4 = (L & 63) * 4;
        int rr = r0 + r;
        float4 v = make_float4(0.f, 0.f, 0.f, 0.f);
        if (rr < R_) v = *(const float4*)(S + (size_t)rr * 256 + c4);
        *(float4*)&As[r][c4] = v;
    }
    __syncthreads();
    bool isq = bx < 8;
    const float* W = isq ? Wx_e : W_sd;
    int NC = isq ? 1024 : 256;
    int n0 = (isq ? bx : bx - 8) * 128;
    int rg = t >> 5, cg = t & 31;
    float acc[2][4] = {};
    const float* wp = W + n0 + 4 * cg;
#pragma unroll 2
    for (int kb = 0; kb < 64; kb++) {
        float4 w0 = *(const float4*)(wp + (size_t)(4 * kb + 0) * NC);
        float4 w1 = *(const float4*)(wp + (size_t)(4 * kb + 1) * NC);
        float4 w2 = *(const float4*)(wp + (size_t)(4 * kb + 2) * NC);
        float4 w3 = *(const float4*)(wp + (size_t)(4 * kb + 3) * NC);
#pragma unroll
        for (int i = 0; i < 2; i++) {
            float4 a = *(const float4*)&As[rg * 2 + i][4 * kb];
            acc[i][0] = fmaf(a.x, w0.x, acc[i][0]);
            acc[i][1] = fmaf(a.x, w0.y, acc[i][1]);
            acc[i][2] = fmaf(a.x, w0.z, acc[i][2]);
            acc[i][3] = fmaf(a.x, w0.w, acc[i][3]);
            acc[i][0] = fmaf(a.y, w1.x, acc[i][0]);
            acc[i][1] = fmaf(a.y, w1.y, acc[i][1]);
            acc[i][2] = fmaf(a.y, w1.z, acc[i][2]);
            acc[i][3] = fmaf(a.y, w1.w, acc[i][3]);
            acc[i][0] = fmaf(a.z, w2.x, acc[i][0]);
            acc[i][1] = fmaf(a.z, w2.y, acc[i][1]);
            acc[i][2] = fmaf(a.z, w2.z, acc[i][2]);
            acc[i][3] = fmaf(a.z, w2.w, acc[i][3]);
            acc[i][0] = fmaf(a.w, w3.x, acc[i][0]);
            acc[i][1] = fmaf(a.w, w3.y, acc[i][1]);
            acc[i][2] = fmaf(a.w, w3.z, acc[i][2]);
            acc[i][3] = fmaf(a.w, w3.w, acc[i][3]);
        }
    }
    int col = n0 + 4 * cg;
#pragma unroll
    for (int i = 0; i < 2; i++) {
        int r = r0 + rg * 2 + i;
        if (r < R_) {
            float4 o = make_float4(acc[i][0], acc[i][1], acc[i][2], acc[i][3]);
            if (isq) {
                *(float4*)&q[(size_t)r * 1024 + col] = o;
                float4 hwv = *(const float4*)&hw[col];   // ve0 = hw - q (h0 rows identical)
                float4 v0 = make_float4(hwv.x - o.x, hwv.y - o.y, hwv.z - o.z, hwv.w - o.w);
                *(float4*)&ve0[(size_t)r * 1024 + col] = v0;
            } else {
                *(float4*)&r_[(size_t)r * 256 + col] = o;
                int b = r / N_, n = r - b * N_;
                rT[((size_t)b * 256 + col + 0) * 128 + n] = o.x;
                rT[((size_t)b * 256 + col + 1) * 128 + n] = o.y;
                rT[((size_t)b * 256 + col + 2) * 128 + n] = o.z;
                rT[((size_t)b * 256 + col + 3) * 128 + n] = o.w;
            }
        }
    }
}

// ============ LSTM steps 0+1 fused: Wh slice staged in LDS ============
__global__ __launch_bounds__(256) void lstm_first(const float* __restrict__ xz,
        const float* __restrict__ Wh, float* __restrict__ hbuf, float* __restrict__ cbuf) {
    __shared__ float Wh_s[256][64];
    __shared__ float h_s[32][260];
    __shared__ float zs[32][68];
    int t = threadIdx.x;
    int ct = blockIdx.x, st = blockIdx.y;
    int et0 = ct * 16, s0 = st * 32;
#pragma unroll
    for (int m = 0; m < 16; m++) {
        int L = m * 256 + t;
        int k = L >> 4, f = L & 15;
        int gg = f >> 2, qq = f & 3;
        *(float4*)&Wh_s[k][f * 4] = *(const float4*)&Wh[(size_t)k * 1024 + gg * 256 + et0 + qq * 4];
    }
    for (int seq = 0; seq < 32; seq++) {
        const float* z0 = xz + ((size_t)(s0 + seq) * T_) * 1024;
        float gi = z0[t], gg = z0[512 + t], go = z0[768 + t];
        float c0v = sigm(gi) * tanh_f(gg);
        h_s[seq][t] = sigm(go) * tanh_f(c0v);
    }
    float creg[2];
    {
        int sqA = t >> 4, e = et0 + (t & 15);
#pragma unroll
        for (int u = 0; u < 2; u++) {
            const float* z0 = xz + ((size_t)(s0 + sqA + u * 16) * T_) * 1024;
            creg[u] = sigm(z0[e]) * tanh_f(z0[512 + e]);
        }
    }
    __syncthreads();
    {
        int sp = (t >> 4) & 15, cq = t & 15;
        int g = cq >> 2, q4 = cq & 3;
        int gcol = g * 256 + et0 + q4 * 4;
        float4 a0 = *(const float4*)(xz + ((size_t)(s0 + sp) * T_ + 1) * 1024 + gcol);
        float4 a1 = *(const float4*)(xz + ((size_t)(s0 + sp + 16) * T_ + 1) * 1024 + gcol);
#pragma unroll 4
        for (int k = 0; k < 256; k++) {
            float4 w4 = *(const float4*)&Wh_s[k][cq * 4];
            float hA = h_s[sp][k];
            float hB = h_s[sp + 16][k];
            a0.x = fmaf(hA, w4.x, a0.x); a0.y = fmaf(hA, w4.y, a0.y);
            a0.z = fmaf(hA, w4.z, a0.z); a0.w = fmaf(hA, w4.w, a0.w);
            a1.x = fmaf(hB, w4.x, a1.x); a1.y = fmaf(hB, w4.y, a1.y);
            a1.z = fmaf(hB, w4.z, a1.z); a1.w = fmaf(hB, w4.w, a1.w);
        }
        *(float4*)&zs[sp][cq * 4] = a0;
        *(float4*)&zs[sp + 16][cq * 4] = a1;
    }
    __syncthreads();
    {
        int sqA = t >> 4, e = t & 15;
#pragma unroll
        for (int u = 0; u < 2; u++) {
            int seq = sqA + u * 16;
            float gi = zs[seq][e], gf = zs[seq][16 + e], gg = zs[seq][32 + e], go = zs[seq][48 + e];
            float cn = sigm(gf) * creg[u] + sigm(gi) * tanh_f(gg);
            size_t gidx = (size_t)(s0 + seq) * H_ + et0 + e;
            cbuf[gidx] = cn;
            hbuf[gidx] = sigm(go) * tanh_f(cn);
        }
    }
}

// ============ LSTM one step (steps 2..7): Wh slice staged in LDS ============
__global__ __launch_bounds__(256) void lstm_step(int step, const float* __restrict__ xz,
        const float* __restrict__ Wh, float* __restrict__ hbuf, float* __restrict__ cbuf) {
    __shared__ float Wh_s[256][64];
    __shared__ float h_s[32][260];
    __shared__ float zs[32][68];
    int t = threadIdx.x;
    int ct = blockIdx.x, st = blockIdx.y;
    int et0 = ct * 16, s0 = st * 32;
    int sp = t >> 4, cq = t & 15;
    int g = cq >> 2, q4 = cq & 3;
    int gcol = g * 256 + et0 + q4 * 4;
    float4 a0 = *(const float4*)(xz + ((size_t)(s0 + sp) * T_ + step) * 1024 + gcol);
    float4 a1 = *(const float4*)(xz + ((size_t)(s0 + sp + 16) * T_ + step) * 1024 + gcol);
#pragma unroll
    for (int m = 0; m < 16; m++) {
        int L = m * 256 + t;
        int k = L >> 4, f = L & 15;
        int gg = f >> 2, qq = f & 3;
        *(float4*)&Wh_s[k][f * 4] = *(const float4*)&Wh[(size_t)k * 1024 + gg * 256 + et0 + qq * 4];
    }
#pragma unroll
    for (int m = 0; m < 8; m++) {
        int L = m * 256 + t;
        int seq = L >> 6, c4 = (L & 63) * 4;
        *(float4*)&h_s[seq][c4] = *(const float4*)&hbuf[(size_t)(s0 + seq) * H_ + c4];
    }
    __syncthreads();
#pragma unroll 4
    for (int k = 0; k < 256; k++) {
        float4 w4 = *(const float4*)&Wh_s[k][cq * 4];
        float h0 = h_s[sp][k];
        float h1 = h_s[sp + 16][k];
        a0.x = fmaf(h0, w4.x, a0.x); a0.y = fmaf(h0, w4.y, a0.y);
        a0.z = fmaf(h0, w4.z, a0.z); a0.w = fmaf(h0, w4.w, a0.w);
        a1.x = fmaf(h1, w4.x, a1.x); a1.y = fmaf(h1, w4.y, a1.y);
        a1.z = fmaf(h1, w4.z, a1.z); a1.w = fmaf(h1, w4.w, a1.w);
    }
    *(float4*)&zs[sp][cq * 4] = a0;
    *(float4*)&zs[sp + 16][cq * 4] = a1;
    __syncthreads();
    int seqA = t >> 4, e = t & 15;
#pragma unroll
    for (int u = 0; u < 2; u++) {
        int seq = seqA + u * 16;
        float gi = zs[seq][e], gf = zs[seq][16 + e], gg = zs[seq][32 + e], go = zs[seq][48 + e];
        size_t gidx = (size_t)(s0 + seq) * H_ + et0 + e;
        float cnew = sigm(gf) * cbuf[gidx] + sigm(gi) * tanh_f(gg);
        cbuf[gidx] = cnew;
        hbuf[gidx] = sigm(go) * tanh_f(cnew);
    }
}

// ============ cumsum: stage whole batch in LDS, scan in-LDS ============
__global__ __launch_bounds__(1024) void cumsum_k(const float* __restrict__ stmt,
                                                 float* __restrict__ pref) {
    __shared__ float buf[96][256];       // 98.3 KB
    int b = blockIdx.x, t = threadIdx.x;
#pragma unroll
    for (int m = 0; m < 6; m++) {        // 6144 float4, coalesced, independent
        int L = m * 1024 + t;
        int r = L >> 6, c4 = (L & 63) * 4;
        *(float4*)&buf[r][c4] = *(const float4*)(stmt + ((size_t)b * NS_ + r) * 256 + c4);
    }
    __syncthreads();
    if (t < 256) {
        float run = 0.0f;
        pref[((size_t)b * N_) * H_ + t] = 0.0f;
        for (int n = 1; n < N_; n++) {
            run += buf[n - 1][t];
            pref[((size_t)b * N_ + n) * H_ + t] = run;
        }
    }
}

// ============ ONCE: logits + masked softmax (layer-invariant) ============
__global__ void softmax_once(const float* __restrict__ r, const float* __restrict__ rT,
                             const float* __restrict__ ck, const float* __restrict__ Wd1,
                             const int* __restrict__ code_length,
                             float* __restrict__ spT_mid, float* __restrict__ spT0,
                             float* __restrict__ spT5) {
    __shared__ float ri[H_], ckl[H_], wd[H_];
    __shared__ float part[8][128];
    __shared__ float red[128];
    int t = threadIdx.x;             // 0..1023
    int j = t & 127, half = t >> 7;
    int bi = blockIdx.x;
    int b = bi / N_, i = bi % N_;
    if (t < H_) {
        ri[t] = r[(size_t)bi * H_ + t];
        ckl[t] = ck[t];
        wd[t] = Wd1[256 + t];
    }
    __syncthreads();
    int len = code_length[b] / T_;
    bool valid = (j < N_) && ((j > i && j <= len) || (j == len));
    float acc = 0.0f;
    if (valid) {
        const float* rTb = rT + (size_t)b * H_ * 128 + j;
        int h0 = half * 32;
#pragma unroll 4
        for (int hh = 0; hh < 32; hh++) {
            int h = h0 + hh;
            float v = rTb[(size_t)h * 128] - ri[h] + ckl[h];
            acc = fmaf(fmaxf(v, 0.0f), wd[h], acc);
        }
    }
    part[half][j] = acc;
    __syncthreads();
    float logit = -3.0e38f;
    if (t < 128) {
        if (valid)
            logit = part[0][j] + part[1][j] + part[2][j] + part[3][j]
                  + part[4][j] + part[5][j] + part[6][j] + part[7][j];
        red[j] = logit;
    }
    __syncthreads();
    for (int off = 64; off; off >>= 1) {
        if (t < off) red[t] = fmaxf(red[t], red[t + off]);
        __syncthreads();
    }
    float m = red[0];
    __syncthreads();
    float e = (t < 128 && valid) ? __builtin_amdgcn_exp2f(1.44269504f * (logit - m)) : 0.0f;
    if (t < 128) red[j] = e;
    __syncthreads();
    for (int off = 64; off; off >>= 1) {
        if (t < off) red[t] += red[t + off];
        __syncthreads();
    }
    float s = red[0];
    if (t < 128 && j < N_) {
        size_t o = ((size_t)b * N_ + j) * 128 + i;
        spT_mid[o] = e / s;
        spT0[o] = (j == 1) ? 1.0f : 0.0f;
        spT5[o] = (j == len) ? 1.0f : 0.0f;
    }
}

// ============ per-layer aggregate: gates = q[j] + ve[i]; 512 thr ============
__global__ __launch_bounds__(512) void aggregate(const float* __restrict__ q,
        const float* __restrict__ ve, const float* __restrict__ spT,
        const float* __restrict__ p, const float* __restrict__ cc,
        const float* __restrict__ hc, float* __restrict__ cn,
        float* __restrict__ hn, float* __restrict__ pn) {
    __shared__ float qj[1024];
    __shared__ float wcol[128];
    __shared__ float red[128];
    __shared__ int vlist[128];
    __shared__ int nv_s;
    __shared__ float parts[2][2][H_];
    int t = threadIdx.x;
    int bj = blockIdx.x;
    int b = bj / N_, j = bj - b * N_;
    if (t < 128) {
        float wv = (t < N_) ? spT[(size_t)bj * 128 + t] * p[b * N_ + t] : 0.f;
        wcol[t] = wv;
        red[t] = wv;
    }
    __syncthreads();
    if (t == 0) {
        int nv = 0;
        for (int i = 0; i < N_; i++)
            if (wcol[i] != 0.0f) vlist[nv++] = i;
        nv_s = nv;
    }
    __syncthreads();
    for (int off = 64; off; off >>= 1) {
        if (t < off) red[t] += red[t + off];
        __syncthreads();
    }
    float wsum = red[0];
    if (wsum == 0.0f) {
        if (t < 256) {
            cn[(size_t)bj * H_ + t] = 0.0f;
            hn[(size_t)bj * H_ + t] = 0.0f;
            if (t == 0) pn[bj] = 0.0f;
        }
        return;
    }
    qj[t] = q[(size_t)bj * 1024 + t];
    qj[512 + t] = q[(size_t)bj * 1024 + 512 + t];
    __syncthreads();
    int hh = t & 255, vs = t >> 8;
    int nv = nv_s;
    float ac = 0.f, ah = 0.f;
    for (int v = vs; v < nv; v += 2) {
        int i = vlist[v];
        float wv = wcol[i];
        size_t rowi = (size_t)b * N_ + i;
        if (j > i) {
            const float* vei = ve + rowi * 1024;
            float gi = qj[hh] + vei[hh];
            float gf = qj[256 + hh] + vei[256 + hh];
            float gg = qj[512 + hh] + vei[512 + hh];
            float go = qj[768 + hh] + vei[768 + hh];
            float c2 = cc[rowi * H_ + hh];
            float cp = sigm(gf) * c2 + sigm(gi) * tanh_f(gg);
            float hp = sigm(go) * tanh_f(cp);
            ac = fmaf(wv, cp, ac);
            ah = fmaf(wv, hp, ah);
        } else {
            ac = fmaf(wv, cc[rowi * H_ + hh], ac);
            ah = fmaf(wv, hc[rowi * H_ + hh], ah);
        }
    }
    parts[vs][0][hh] = ac;
    parts[vs][1][hh] = ah;
    __syncthreads();
    if (t < 256) {
        float inv = __builtin_amdgcn_rcpf(wsum + 1e-7f);
        cn[(size_t)bj * H_ + t] = (parts[0][0][t] + parts[1][0][t]) * inv;
        hn[(size_t)bj * H_ + t] = (parts[0][1][t] + parts[1][1][t]) * inv;
        if (t == 0) pn[bj] = wsum;
    }
}

// ---------------- host launcher ----------------

extern "C" void kernel_launch(void* const* d_in, const int* in_sizes, int n_in,
                              void* d_out, int out_size, void* d_ws, size_t ws_size,
                              hipStream_t stream) {
    const int*   code_statements = (const int*)d_in[0];
    const int*   code_length = (const int*)d_in[1];
    const float* embed = (const float*)d_in[2];
    const float* Wx_s = (const float*)d_in[3];
    const float* Wh_s = (const float*)d_in[4];
    const float* b_s  = (const float*)d_in[5];
    const float* W_se = (const float*)d_in[6];
    const float* b_se = (const float*)d_in[7];
    const float* Wx_e = (const float*)d_in[8];
    const float* Wh_e = (const float*)d_in[9];
    const float* b_e  = (const float*)d_in[10];
    const float* W_sd = (const float*)d_in[13];
    const float* b_sd = (const float*)d_in[14];
    const float* W_d1 = (const float*)d_in[15];
    // d_in[11] W_hk, d_in[12] b_hk, d_in[16] b_d1: softmax-invariant -> unused
    const float* init_a = (const float*)d_in[17];
    const float* init_b = (const float*)d_in[18];
    float* out = (float*)d_out;

    float* wsf = (float*)d_ws;
    size_t off = 0;
    auto alloc = [&](size_t n) { float* p = wsf + off; off += n; return p; };
    float* cz = alloc(1024);
    float* ck = alloc(256);
    float* hw = alloc(1024);             // init_b@Wh_e + cz
    float* xz = alloc((size_t)3072 * 1024);
    float* stmt = alloc(384 * 256);      // LSTM h buffer
    float* cls = alloc(384 * 256);       // LSTM cell state
    float* pref = alloc(R_ * 256);
    float* s_   = alloc(R_ * 256);       // pref @ W_se
    float* q  = alloc(R_ * 1024);
    float* r_ = alloc(R_ * 256);
    float* rT = alloc(4 * 256 * 128);
    float* ve = alloc(R_ * 1024);        // h@Wh_e + cz - q
    float* spT_mid = alloc(R_ * 128);
    float* spT0    = alloc(R_ * 128);
    float* spT5    = alloc(R_ * 128);
    float* p0 = alloc(R_);
    float* p1 = alloc(R_);
    float* c0 = alloc(R_ * 256);
    float* c1 = alloc(R_ * 256);
    float* h0 = alloc(R_ * 256);
    float* h1 = alloc(R_ * 256);

    // one prologue launch: xz (64x128 tiles) + cz/ck/hw + state init
    prologue<<<dim3(438), 512, 0, stream>>>(code_statements, embed, Wx_s, b_s,
                                            b_se, Wx_e, b_e, W_sd, b_sd, Wh_e,
                                            init_a, init_b, xz, cz, ck, hw, c0, h0, p0);
    // LSTM: steps 0+1 fused, then 2..7 (Wh staged in LDS)
    lstm_first<<<dim3(16, 12), 256, 0, stream>>>(xz, Wh_s, stmt, cls);
    for (int step = 2; step < T_; step++)
        lstm_step<<<dim3(16, 12), 256, 0, stream>>>(step, xz, Wh_s, stmt, cls);
    cumsum_k<<<dim3(4), 1024, 0, stream>>>(stmt, pref);
    gemm_t<16><<<dim3(2, 25), 256, 0, stream>>>(pref, W_se, nullptr, nullptr, nullptr,
                                                s_, R_, 256);
    qr_kernel<<<dim3(10, 25), 256, 0, stream>>>(s_, Wx_e, W_sd, hw, q, ve, r_, rT);
    softmax_once<<<dim3(R_), 1024, 0, stream>>>(r_, rT, ck, W_d1, code_length,
                                                spT_mid, spT0, spT5);

    // execution layers (ve0 already produced by qr_kernel)
    for (int layer = 0; layer < NL_; layer++) {
        bool odd = (layer & 1);
        float* pc = odd ? p1 : p0;
        float* pn = odd ? p0 : p1;
        float* cc = odd ? c1 : c0;
        float* cn = odd ? c0 : c1;
        float* hc = odd ? h1 : h0;
        float* hn = odd ? h0 : h1;
        if (layer == NL_ - 1) hn = out;  // final h straight to d_out
        const float* spT = (layer == 0) ? spT0 : (layer == NL_ - 1) ? spT5 : spT_mid;
        aggregate<<<dim3(R_), 512, 0, stream>>>(q, ve, spT, pc, cc, hc, cn, hn, pn);
        if (layer < NL_ - 1)
            gemm_t<16><<<dim3(8, 25), 256, 0, stream>>>(hn, Wh_e, cz, q, pn,
                                                        ve, R_, 1024);
    }
}